// Round 10
// baseline (76.364 us; speedup 1.0000x reference)
//
#include <hip/hip_runtime.h>

#define Nn 256
#define Cc 128
#define Pp 275
#define Dd 128

typedef unsigned int u32;
typedef unsigned short u16;
typedef float f32x4 __attribute__((ext_vector_type(4)));
typedef short bf16x8 __attribute__((ext_vector_type(8)));

__device__ __forceinline__ float bf2f(u16 h) {
    return __uint_as_float(((u32)h) << 16);
}
__device__ __forceinline__ u16 f2bf(float f) {
    u32 u = __float_as_uint(f);
    return (u16)((u + 0x7fffu + ((u >> 16) & 1u)) >> 16);
}

// ---------------- K1: bias_t / bias_p (N x D) + f->bf16 + Wl^T bf16 ----------------
__global__ __launch_bounds__(256) void bias_kernel(
    const float* __restrict__ m_t, const float* __restrict__ m_p,
    const float* __restrict__ c_t, const float* __restrict__ c_p,
    const float* __restrict__ W, const float* __restrict__ b,
    const float* __restrict__ f,
    float* __restrict__ bias_t, float* __restrict__ bias_p,
    u16* __restrict__ f_bf, u16* __restrict__ WlT)
{
    int idx = blockIdx.x * 256 + threadIdx.x;   // N*D = 32768
    int n = idx >> 7, d = idx & 127;
    float at = 0.f, ap = 0.f;
#pragma unroll 8
    for (int k = 0; k < 64; ++k) {
        float wm = W[(128 + k) * 128 + d];
        float wc = W[(192 + k) * 128 + d];
        at = fmaf(m_t[n * 64 + k], wm, at);
        at = fmaf(c_t[n * 64 + k], wc, at);
        ap = fmaf(m_p[n * 64 + k], wm, ap);
        ap = fmaf(c_p[n * 64 + k], wc, ap);
    }
    float bb = b[d];
    bias_t[idx] = at + bb;
    bias_p[idx] = ap + bb;
    f_bf[idx] = f2bf(f[idx]);
    if (idx < 16384) {                 // WlT[d][c] = Wl[c][d]
        int dd = idx >> 7, cc = idx & 127;
        WlT[idx] = f2bf(W[cc * 128 + dd]);
    }
}

// ---------------- K2: join — coalesced LDS-staged x, MFMA ----------------
// grid (9, 256): block = one n, 32-p chunk; 256 thr = 4 waves.
// Stage: x[n][c][p0..p0+31] fp32 -> LDS [p][c] bf16 (XOR-swizzled), float4 reads.
// Compute: wave w: tile tw=w>>1 (16 p), dt-half w&1; A = ds_read_b128.
__global__ __launch_bounds__(256) void join_stage_kernel(
    const float* __restrict__ x_t, const float* __restrict__ x_p,
    const u16* __restrict__ WlT,
    const float* __restrict__ bias_t, const float* __restrict__ bias_p,
    u16* __restrict__ pred, u16* __restrict__ pos)
{
    __shared__ u16 wlds[128 * 128];    // 32 KB swizzled WlT
    __shared__ u16 xt_lds[32 * 128];   // 8 KB  [p][c] bf16
    __shared__ u16 xp_lds[32 * 128];   // 8 KB
    const int tid = threadIdx.x;
    const int chunk = blockIdx.x;      // 0..8
    const int n = blockIdx.y;
    const int p0 = chunk * 32;

    {   // stage WlT swizzled: 2048 uint4 over 256 threads
        const uint4* src = reinterpret_cast<const uint4*>(WlT);
#pragma unroll
        for (int it = 0; it < 8; ++it) {
            int j = tid + 256 * it;
            int row = j >> 4;
            int colb = (j & 15) << 4;
            uint4 v = src[j];
            *reinterpret_cast<uint4*>((char*)wlds + row * 256 + (colb ^ ((row & 7) << 4))) = v;
        }
    }

    {   // stage x tiles: thread: p4 = tid&7 (4 p's), cg = tid>>3 (c-pair base)
        const float* xbt = x_t + (size_t)n * (Cc * Pp);
        const float* xbp = x_p + (size_t)n * (Cc * Pp);
        const int p4 = tid & 7;
        const int prow = p0 + p4 * 4;
        const bool full = (prow + 3 < Pp);
#pragma unroll
        for (int j = 0; j < 2; ++j) {
            const int c0 = (tid >> 3) * 2 + 64 * j;   // even; rows c0, c0+1
            float a0[4], a1[4], b0[4], b1[4];
            if (full) {
                f32x4 t0 = *reinterpret_cast<const f32x4*>(xbt + (size_t)c0 * Pp + prow);
                f32x4 t1 = *reinterpret_cast<const f32x4*>(xbt + (size_t)(c0 + 1) * Pp + prow);
                f32x4 q0 = *reinterpret_cast<const f32x4*>(xbp + (size_t)c0 * Pp + prow);
                f32x4 q1 = *reinterpret_cast<const f32x4*>(xbp + (size_t)(c0 + 1) * Pp + prow);
#pragma unroll
                for (int e = 0; e < 4; ++e) { a0[e]=t0[e]; a1[e]=t1[e]; b0[e]=q0[e]; b1[e]=q1[e]; }
            } else {
#pragma unroll
                for (int e = 0; e < 4; ++e) {
                    int pe = prow + e; if (pe > Pp - 1) pe = Pp - 1;
                    a0[e] = xbt[(size_t)c0 * Pp + pe];
                    a1[e] = xbt[(size_t)(c0 + 1) * Pp + pe];
                    b0[e] = xbp[(size_t)c0 * Pp + pe];
                    b1[e] = xbp[(size_t)(c0 + 1) * Pp + pe];
                }
            }
#pragma unroll
            for (int e = 0; e < 4; ++e) {
                const int pl = p4 * 4 + e;
                const int cb = (c0 * 2) ^ ((pl & 7) << 4);
                *reinterpret_cast<u32*>((char*)xt_lds + pl * 256 + cb) =
                    (u32)f2bf(a0[e]) | ((u32)f2bf(a1[e]) << 16);
                *reinterpret_cast<u32*>((char*)xp_lds + pl * 256 + cb) =
                    (u32)f2bf(b0[e]) | ((u32)f2bf(b1[e]) << 16);
            }
        }
    }

    __syncthreads();

    const int w = tid >> 6;
    const int l = tid & 63;
    const int tw = w >> 1;                 // p-tile within chunk (0/1)
    const int dt0 = (w & 1) * 4;           // dt half
    const int g = l >> 4;
    const int pl_in = tw * 16 + (l & 15);  // A-frag row

    bf16x8 At[4], Ap[4];
#pragma unroll
    for (int kk = 0; kk < 4; ++kk) {
        const int cb = (kk * 64 + g * 16) ^ ((pl_in & 7) << 4);
        At[kk] = *reinterpret_cast<const bf16x8*>((const char*)xt_lds + pl_in * 256 + cb);
        Ap[kk] = *reinterpret_cast<const bf16x8*>((const char*)xp_lds + pl_in * 256 + cb);
    }

    float bvT[4], bvP[4];
#pragma unroll
    for (int i = 0; i < 4; ++i) {
        int d = (dt0 + i) * 16 + (l & 15);
        bvT[i] = bias_t[n * 128 + d];
        bvP[i] = bias_p[n * 128 + d];
    }

#pragma unroll
    for (int i = 0; i < 4; ++i) {
        const int dt = dt0 + i;
        bf16x8 B[4];
        const int row = dt * 16 + (l & 15);
#pragma unroll
        for (int kk = 0; kk < 4; ++kk) {
            int cbyte = kk * 64 + (g << 4);
            B[kk] = *reinterpret_cast<const bf16x8*>(
                (const char*)wlds + row * 256 + (cbyte ^ ((row & 7) << 4)));
        }
        f32x4 aT = {0.f, 0.f, 0.f, 0.f}, aP = {0.f, 0.f, 0.f, 0.f};
#pragma unroll
        for (int kk = 0; kk < 4; ++kk) {
            aT = __builtin_amdgcn_mfma_f32_16x16x32_bf16(At[kk], B[kk], aT, 0, 0, 0);
            aP = __builtin_amdgcn_mfma_f32_16x16x32_bf16(Ap[kk], B[kk], aP, 0, 0, 0);
        }
        const int d = dt * 16 + (l & 15);
#pragma unroll
        for (int r = 0; r < 4; ++r) {
            int p = p0 + tw * 16 + g * 4 + r;
            if (p < Pp) {
                size_t o = ((size_t)p * Nn + n) * Dd + d;
                pred[o] = f2bf(aT[r] + bvT[i]);
                pos[o]  = f2bf(aP[r] + bvP[i]);
            }
        }
    }
}

// ---------------- K3: MFMA logits + fixed-shift LSE - diag (R8 best form) ----------
// grid (2, Pp): sel = blockIdx.x; 512 threads = 8 waves; wave w rows w*32..+31.
__global__ __launch_bounds__(512) void logits_mfma_kernel(
    const u16* __restrict__ f_bf,
    const u16* __restrict__ pred, const u16* __restrict__ pos,
    float* __restrict__ partial)
{
    __shared__ u16 lds[Nn * Dd];   // 64 KB swizzled pos[p] tile
    const int tid = threadIdx.x;
    const int sel = blockIdx.x;
    const int p = blockIdx.y;
    const int w = tid >> 6;
    const int l = tid & 63;
    const int r0 = w * 32;

    {
        const uint4* src = reinterpret_cast<const uint4*>(pos + (size_t)p * (Nn * Dd));
#pragma unroll
        for (int it = 0; it < 8; ++it) {
            int j = tid + 512 * it;
            int row = j >> 4;
            int colb = (j & 15) << 4;
            uint4 v = src[j];
            *reinterpret_cast<uint4*>((char*)lds + row * 256 + (colb ^ ((row & 7) << 4))) = v;
        }
    }

    const u16* Abase = sel ? (pred + (size_t)p * (Nn * Dd)) : f_bf;
    bf16x8 A[2][4];
    {
        const int arow = l & 15;
        const int acol = (l >> 4) << 4;
#pragma unroll
        for (int rt = 0; rt < 2; ++rt)
#pragma unroll
            for (int kk = 0; kk < 4; ++kk) {
                const char* ap = (const char*)Abase
                               + (size_t)(r0 + rt * 16 + arow) * 256 + kk * 64 + acol;
                A[rt][kk] = *reinterpret_cast<const bf16x8*>(ap);
            }
    }

    __syncthreads();

    const float L2E = 1.4426950408889634f;
    float s_[2][4];
    float dg[2][4];
#pragma unroll
    for (int rt = 0; rt < 2; ++rt)
#pragma unroll
        for (int r = 0; r < 4; ++r) { s_[rt][r] = 0.f; dg[rt][r] = 0.f; }

    const int mcol = l & 15;
    const int bcol = (l >> 4) << 4;

    for (int ct = 0; ct < 16; ++ct) {
        bf16x8 B[4];
        const int mrow = ct * 16 + mcol;
#pragma unroll
        for (int kk = 0; kk < 4; ++kk) {
            int cb = kk * 64 + bcol;
            B[kk] = *reinterpret_cast<const bf16x8*>(
                (const char*)lds + mrow * 256 + (cb ^ ((mrow & 7) << 4)));
        }
#pragma unroll
        for (int rt = 0; rt < 2; ++rt) {
            f32x4 acc = {0.f, 0.f, 0.f, 0.f};
#pragma unroll
            for (int kk = 0; kk < 4; ++kk)
                acc = __builtin_amdgcn_mfma_f32_16x16x32_bf16(A[rt][kk], B[kk], acc, 0, 0, 0);
            const bool isdg_ct = (ct == ((r0 >> 4) + rt));
#pragma unroll
            for (int r = 0; r < 4; ++r) {
                float v = acc[r];
                s_[rt][r] += __builtin_amdgcn_exp2f(fmaf(v, L2E, -64.f));
                if (isdg_ct && ((l & 15) == (((l >> 4) << 2) + r))) dg[rt][r] = v;
            }
        }
    }

    float local = 0.f;
#pragma unroll
    for (int rt = 0; rt < 2; ++rt)
#pragma unroll
        for (int r = 0; r < 4; ++r) {
            float s = s_[rt][r];
            s += __shfl_xor(s, 1);
            s += __shfl_xor(s, 2);
            s += __shfl_xor(s, 4);
            s += __shfl_xor(s, 8);
            if ((l & 15) == (((l >> 4) << 2) + r))
                local += 0.6931471805599453f * (64.f + __log2f(s)) - dg[rt][r];
        }

    __syncthreads();
    float* red = reinterpret_cast<float*>(lds);
    red[tid] = local;
    __syncthreads();
    for (int k = 256; k > 0; k >>= 1) {
        if (tid < k) red[tid] += red[tid + k];
        __syncthreads();
    }
    if (tid == 0) partial[p * 2 + sel] = red[0];
}

// ---------------- K4: deterministic final reduce ----------------
__global__ __launch_bounds__(256) void reduce_kernel(
    const float* __restrict__ partial, float* __restrict__ out)
{
    __shared__ float red[256];
    float s = 0.f;
    for (int i = threadIdx.x; i < 2 * Pp; i += 256) s += partial[i];
    red[threadIdx.x] = s;
    __syncthreads();
    for (int k = 128; k > 0; k >>= 1) {
        if (threadIdx.x < k) red[threadIdx.x] += red[threadIdx.x + k];
        __syncthreads();
    }
    if (threadIdx.x == 0) out[0] = red[0] * (1.0f / (Pp * (float)Nn));
}

extern "C" void kernel_launch(void* const* d_in, const int* in_sizes, int n_in,
                              void* d_out, int out_size, void* d_ws, size_t ws_size,
                              hipStream_t stream)
{
    const float* f   = (const float*)d_in[0];
    const float* x_t = (const float*)d_in[1];
    const float* x_p = (const float*)d_in[2];
    const float* m_t = (const float*)d_in[3];
    const float* m_p = (const float*)d_in[4];
    const float* c_t = (const float*)d_in[5];
    const float* c_p = (const float*)d_in[6];
    const float* W   = (const float*)d_in[7];
    const float* b   = (const float*)d_in[8];

    char* ws = (char*)d_ws;
    const size_t SLAB = (size_t)Pp * Nn * Dd;     // 9,011,200 elems

    float* bias_t = (float*)ws;                          // 131072 B
    float* bias_p = bias_t + Nn * Dd;                    // 131072 B
    u16* f_bf = (u16*)(ws + 262144);                     // 65536 B
    u16* WlT  = f_bf + Nn * Dd;                          // 32768 B
    u16* pred = (u16*)(ws + 360448);
    u16* pos  = pred + SLAB;
    float* partial = (float*)(pos + SLAB);

    bias_kernel<<<dim3(Nn * Dd / 256), 256, 0, stream>>>(m_t, m_p, c_t, c_p, W, b, f,
                                                         bias_t, bias_p, f_bf, WlT);
    join_stage_kernel<<<dim3(9, Nn), 256, 0, stream>>>(x_t, x_p, WlT, bias_t, bias_p,
                                                       pred, pos);
    logits_mfma_kernel<<<dim3(2, Pp), 512, 0, stream>>>(f_bf, pred, pos, partial);
    reduce_kernel<<<1, 256, 0, stream>>>(partial, (float*)d_out);
}